// Round 2
// baseline (266.038 us; speedup 1.0000x reference)
//
#include <hip/hip_runtime.h>

#define MAXLEN 100
#define HDIM 64
#define CH 4                       // x-staging chunk length (steps)
#define NSEG 12                    // segments per block (12 real rows of 16)
#define SROW 72                    // ushorts per bf16 x step-row (144 B)
#define SPLANE (CH * SROW + 8)     // 296 ushorts per segment plane
#define HSTR 72                    // ushorts per h row (144 B)
#define L2E 1.44269504f

typedef __attribute__((ext_vector_type(8))) short bf16x8;
typedef __attribute__((ext_vector_type(4))) float f32x4;

// Step barrier: LDS-only consistency (no implicit vmcnt(0) drain), so the
// chunk-ahead x prefetch stays in flight across all step barriers.
#define LGKM_BARRIER() asm volatile("s_waitcnt lgkmcnt(0)\n\ts_barrier" ::: "memory")

// RNE f32x2 -> packed bf16x2 in one instruction (T12 recipe; no builtin on gfx950).
__device__ __forceinline__ unsigned cvtpk(float a, float b) {
    unsigned r;
    asm("v_cvt_pk_bf16_f32 %0, %1, %2" : "=v"(r) : "v"(a), "v"(b));
    return r;
}
__device__ __forceinline__ bf16x8 pack8(f32x4 a, f32x4 b) {
    union { unsigned u[4]; bf16x8 v; } c;
    c.u[0] = cvtpk(a[0], a[1]); c.u[1] = cvtpk(a[2], a[3]);
    c.u[2] = cvtpk(b[0], b[1]); c.u[3] = cvtpk(b[2], b[3]);
    return c.v;
}
// Gate activations on PRE-SCALED pre-activations: the -L2E (resp -2*L2E for
// the g gate) factor is folded into the bf16 weights, and the scaled bias is
// the MFMA C-seed, so the exp2 argument arrives ready -> no fma here.
__device__ __forceinline__ float sig_pre(float a) {     // a = -L2E*(z)
    return __builtin_amdgcn_rcpf(1.0f + __builtin_amdgcn_exp2f(a));
}
__device__ __forceinline__ float tanh_pre(float a) {    // a = -2*L2E*(z)
    return fmaf(2.0f, __builtin_amdgcn_rcpf(1.0f + __builtin_amdgcn_exp2f(a)), -1.0f);
}
__device__ __forceinline__ float tanh_p(float v) {      // v in true scale
    return fmaf(2.0f, __builtin_amdgcn_rcpf(1.0f + __builtin_amdgcn_exp2f(v * (-2.0f * L2E))), -1.0f);
}

// ---------------------------------------------------------------------------
// Pre-pass P1: thread s in [0,B] computes segStart[s] = lower_bound(index, s)
// via binary search (index sorted, int32); threads s<B also bin the capped
// length into a global histogram. Replaces the N=500k bounds kernel AND the
// histogram half of the old single-block sort (which cost ~16 us together).
// hist must be zeroed before launch (hipMemsetAsync).
// ---------------------------------------------------------------------------
__global__ void seg_hist_kernel(const int* __restrict__ index,
                                int* __restrict__ segStart,
                                int* __restrict__ hist, int N, int B) {
    const int s = blockIdx.x * blockDim.x + threadIdx.x;
    if (s > B) return;
    int lo = 0, hi = N;
    while (lo < hi) { int m = (lo + hi) >> 1; if (index[m] < s) lo = m + 1; else hi = m; }
    segStart[s] = lo;
    if (s < B) {
        int l2 = lo, h2 = N;
        while (l2 < h2) { int m = (l2 + h2) >> 1; if (index[m] < s + 1) l2 = m + 1; else h2 = m; }
        int len = l2 - lo;
        len = len < MAXLEN ? len : MAXLEN;
        atomicAdd(&hist[len], 1);
    }
}

// ---------------------------------------------------------------------------
// Pre-pass P2: parallel scatter. Each of 16 blocks redundantly computes the
// descending exclusive scan of the 101-bucket histogram, then scatters its
// share of segments: slot = base[len] + atomicAdd(global cnt[len]). One
// packed int2 {start, (seg<<7)|len} per slot (was 3 scattered stores).
// cnt must be zeroed before launch. Tail slots get seg=-1.
// ---------------------------------------------------------------------------
__global__ void seg_scatter_kernel(const int* __restrict__ segStart,
                                   const int* __restrict__ hist,
                                   int* __restrict__ cnt,
                                   int2* __restrict__ slotPacked,
                                   int B, int nslots) {
    __shared__ int base_s[MAXLEN + 1];
    const int tid = threadIdx.x;
    __shared__ int hist_s[MAXLEN + 1];
    if (tid <= MAXLEN) hist_s[tid] = hist[tid];
    __syncthreads();
    if (tid == 0) {
        int acc = 0;
        for (int l = MAXLEN; l >= 0; --l) { base_s[l] = acc; acc += hist_s[l]; }
    }
    __syncthreads();
    const int stride = gridDim.x * blockDim.x;
    for (int b = blockIdx.x * blockDim.x + tid; b < B; b += stride) {
        const int s0 = segStart[b];
        int len = segStart[b + 1] - s0;
        len = len < MAXLEN ? len : MAXLEN;
        const int slot = base_s[len] + atomicAdd(&cnt[len], 1);
        slotPacked[slot] = make_int2(s0, (b << 7) | len);
    }
    if (blockIdx.x == 0 && tid < nslots - B) slotPacked[B + tid] = make_int2(0, -128);
}

// 683 blocks x 256 threads; 12 segments/block; 4 waves, wave w owns hidden
// cols [16w,16w+16) for all 4 gates. Segment s -> MFMA A/C row (s/3)*4+(s%3);
// each lane's C regs 0..2 are its 3 real (seg,hid) bundles.
// Per-step MFMA chain split: accx[g] = x_t @ Wih' (h-independent, seeded with
// the scaled bias) runs in the previous step's trans shadow; the serial step
// is acc = mfma(ha1,wh1, mfma(ha0,wh0,accx)).
// NEW vs R1: (a) weights pre-scaled by -L2E/-2L2E and bias folded into the
// MFMA C-seed -> 4 fewer fma per output; (b) all f32->bf16 packing via
// v_cvt_pk_bf16_f32 (1 instr vs ~10 ALU ops) -> COMMIT and h-store VALU cost
// collapses; (c) slot metadata arrives as one packed int2.
__global__ __launch_bounds__(256, 3)
void lstm12_kernel(const float* __restrict__ x,
                   const float* __restrict__ Wih,
                   const float* __restrict__ Whh,
                   const float* __restrict__ bih,
                   const float* __restrict__ bhh,
                   const int* __restrict__ index,
                   const int2* __restrict__ slotPacked,
                   float* __restrict__ out, int N, int B) {
    const int tid  = threadIdx.x;
    const int w    = tid >> 6;
    const int lane = tid & 63;
    const int l15  = lane & 15;
    const int quad = lane >> 4;
    const int segbase = blockIdx.x * NSEG;
    const int ncol = w * 16 + l15;

    __shared__ __align__(16) unsigned short xst[NSEG * SPLANE];  // 7.1 KB
    __shared__ __align__(16) unsigned short hst[2][16][HSTR];    // 4.6 KB
    __shared__ int sstart[NSEG], slen[NSEG], sseg[NSEG];

    // --- per-block segment bounds: packed slots if available, else search ---
    if (tid < NSEG) {
        const int slot = segbase + tid;
        int sg = -1, s = 0, len = 0;
        if (slotPacked != nullptr) {
            const int2 p = slotPacked[slot];
            s   = p.x;
            sg  = p.y >> 7;          // arithmetic: tail slots decode to -1
            len = p.y & 127;
        } else {
            const int b = slot;
            if (b < B) {
                sg = b;
                int lo = 0, hi = N;
                while (lo < hi) { int m = (lo + hi) >> 1; if (index[m] < b) lo = m + 1; else hi = m; }
                s = lo;
                hi = N;
                while (lo < hi) { int m = (lo + hi) >> 1; if (index[m] < b + 1) lo = m + 1; else hi = m; }
                len = lo - s;
                len = len < MAXLEN ? len : MAXLEN;
            }
        }
        sstart[tid] = s;
        slen[tid] = len;
        sseg[tid] = sg;
    }
    for (int i = tid; i < 2 * 16 * HSTR / 2; i += 256) ((int*)hst)[i] = 0;
    __syncthreads();

    // --- weight B-fragments (register-resident), PRE-SCALED by the exp2
    // factor; scaled bias becomes the per-gate MFMA C-seed bsv[g]. ---
    bf16x8 wi[4][2], wh[4][2];
    f32x4 bsv[4];
#pragma unroll
    for (int g = 0; g < 4; ++g) {
        const float sc = (g == 2) ? (-2.0f * L2E) : (-L2E);
        const int row = g * HDIM + ncol;
        const float bb = sc * (bih[row] + bhh[row]);
        bsv[g][0] = bb; bsv[g][1] = bb; bsv[g][2] = bb; bsv[g][3] = bb;
#pragma unroll
        for (int kt = 0; kt < 2; ++kt) {
            const f32x4* pi = (const f32x4*)(Wih + (size_t)row * HDIM + kt * 32 + quad * 8);
            const f32x4* ph = (const f32x4*)(Whh + (size_t)row * HDIM + kt * 32 + quad * 8);
            wi[g][kt] = pack8(pi[0] * sc, pi[1] * sc);
            wh[g][kt] = pack8(ph[0] * sc, ph[1] * sc);
        }
    }

    // Per-lane gate-math metadata: segs quad*3 + r, r in 0..2.
    int len3[3];
#pragma unroll
    for (int r = 0; r < 3; ++r) len3[r] = slen[quad * 3 + r];
    int lmax = 0;
#pragma unroll
    for (int i = 0; i < NSEG; ++i) { int v = slen[i]; lmax = v > lmax ? v : lmax; }
    lmax = __builtin_amdgcn_readfirstlane(lmax);

    // Staging roles: 12 segs x 4 steps x 4 col-groups(16 floats) = 192 units;
    // waves 0..2 stage (tid < 192), wave 3 idle in staging. pre = 16 VGPRs.
    const int sS = tid >> 4, sT = (tid >> 2) & 3, sC = tid & 3;   // valid for tid<192
    const int sst = (tid < 192) ? sstart[sS] : 0;
    const int sln = (tid < 192) ? slen[sS] : 0;

    f32x4 pre[4];

#define ISSUE(t0_)                                                              \
    if (w < 3) {                                                                \
        int ct = (t0_) + sT;                                                    \
        ct = (sln > 0) ? (ct < sln ? ct : sln - 1) : 0;                         \
        int row = sst + ct;                                                     \
        row = row < N - 1 ? row : N - 1;                                        \
        const f32x4* p_ = (const f32x4*)(x + (size_t)row * HDIM + sC * 16);     \
        pre[0] = p_[0]; pre[1] = p_[1]; pre[2] = p_[2]; pre[3] = p_[3];         \
    }
#define COMMIT()                                                                \
    if (w < 3) {                                                                \
        uint4 o1, o2;                                                           \
        o1.x = cvtpk(pre[0][0], pre[0][1]); o1.y = cvtpk(pre[0][2], pre[0][3]); \
        o1.z = cvtpk(pre[1][0], pre[1][1]); o1.w = cvtpk(pre[1][2], pre[1][3]); \
        o2.x = cvtpk(pre[2][0], pre[2][1]); o2.y = cvtpk(pre[2][2], pre[2][3]); \
        o2.z = cvtpk(pre[3][0], pre[3][1]); o2.w = cvtpk(pre[3][2], pre[3][3]); \
        unsigned short* d_ = &xst[sS * SPLANE + sT * SROW + sC * 16];           \
        *(uint4*)d_ = o1; *(uint4*)(d_ + 8) = o2;                               \
    }

    // x A-frag source plane for this lane's A-row m=l15: real seg
    // (m>>2)*3 + min(m&3,2); garbage rows alias a real plane (broadcast, free).
    const int m3 = l15 & 3;
    const int xp = (l15 >> 2) * 3 + (m3 < 2 ? m3 : 2);
    const unsigned short* xb = &xst[xp * SPLANE + quad * 8];

    // accx[g] = bias + x_t @ Wih' for the upcoming step (h-independent).
    f32x4 accx[4];
#define ACCX(tt_)                                                               \
    {                                                                           \
        const unsigned short* xr_ = xb + (tt_) * SROW;                          \
        bf16x8 xa0_ = *(const bf16x8*)(xr_);                                    \
        bf16x8 xa1_ = *(const bf16x8*)(xr_ + 32);                               \
        _Pragma("unroll")                                                       \
        for (int g_ = 0; g_ < 4; ++g_) {                                        \
            f32x4 a_ = __builtin_amdgcn_mfma_f32_16x16x32_bf16(xa0_, wi[g_][0], bsv[g_], 0, 0, 0); \
            accx[g_] = __builtin_amdgcn_mfma_f32_16x16x32_bf16(xa1_, wi[g_][1], a_, 0, 0, 0); \
        }                                                                       \
    }

    float c3[3] = {0, 0, 0}, h3[3] = {0, 0, 0};
    const int nch = (lmax + CH - 1) / CH;

    if (nch > 0) {
        ISSUE(0);
        COMMIT();                      // compiler auto-waits vmcnt for pre use
        LGKM_BARRIER();
        ACCX(0);                       // x-part of step 0
        if (nch > 1) ISSUE(CH);        // chunk 1 in flight across chunk 0's steps

        for (int ch = 0; ch < nch; ++ch) {
            const int t0 = ch * CH;
#pragma unroll
            for (int tt = 0; tt < CH; ++tt) {
                const int t = t0 + tt;          // parity(t) == parity(tt), CH even
                const int pb = tt & 1, nb = pb ^ 1;

                // h-dependent half: 2-deep chain seeded by accx.
                const unsigned short* hr = &hst[pb][l15][quad * 8];
                bf16x8 ha0 = *(const bf16x8*)(hr);
                bf16x8 ha1 = *(const bf16x8*)(hr + 32);

                f32x4 acc[4];
#pragma unroll
                for (int g = 0; g < 4; ++g) {
                    f32x4 a = __builtin_amdgcn_mfma_f32_16x16x32_bf16(ha0, wh[g][0], accx[g], 0, 0, 0);
                    acc[g] = __builtin_amdgcn_mfma_f32_16x16x32_bf16(ha1, wh[g][1], a, 0, 0, 0);
                }

                // x-part of the NEXT step (independent of h): fills the
                // MFMA pipe while this step's gate trans runs.
                if (tt + 1 < CH) ACCX(tt + 1);

                // Gate math: 3 real bundles/lane (C regs 0..2 = segs 3q..3q+2).
                // acc is pre-scaled (incl bias) -> activations are fma-free.
#pragma unroll
                for (int r = 0; r < 3; ++r) {
                    float gi = sig_pre (acc[0][r]);
                    float gf = sig_pre (acc[1][r]);
                    float gg = tanh_pre(acc[2][r]);
                    float go = sig_pre (acc[3][r]);
                    float cn = fmaf(gf, c3[r], gi * gg);
                    float hn = go * tanh_p(cn);
                    const bool up = t < len3[r];
                    c3[r] = up ? cn : c3[r];
                    h3[r] = up ? hn : h3[r];
                    hst[nb][quad * 4 + r][ncol] = (unsigned short)cvtpk(h3[r], h3[r]);
                }
                LGKM_BARRIER();
            }
            if (ch + 1 < nch) {
                COMMIT();                          // chunk ch+1 (vmcnt auto-waited)
                LGKM_BARRIER();
                ACCX(0);                           // x-part of next chunk's step 0
                if (ch + 2 < nch) ISSUE((ch + 2) * CH);
            }
        }
    }

#pragma unroll
    for (int r = 0; r < 3; ++r) {
        const int sg = sseg[quad * 3 + r];
        if (sg >= 0) out[(size_t)sg * HDIM + ncol] = h3[r];
    }
#undef ISSUE
#undef COMMIT
#undef ACCX
}

extern "C" void kernel_launch(void* const* d_in, const int* in_sizes, int n_in,
                              void* d_out, int out_size, void* d_ws, size_t ws_size,
                              hipStream_t stream) {
    const float* x     = (const float*)d_in[0];
    const float* Wih   = (const float*)d_in[1];
    const float* Whh   = (const float*)d_in[2];
    const float* bih   = (const float*)d_in[3];
    const float* bhh   = (const float*)d_in[4];
    const int*   index = (const int*)d_in[5];

    const int N = in_sizes[5];
    const int B = out_size / HDIM;   // 8192

    const int nblocks = (B + NSEG - 1) / NSEG;   // 683
    const int nslots  = nblocks * NSEG;

    // Workspace layout (ints): hist[101] | cnt[101] | pad->204 | segStart[B+1]
    // pad->8-align | slotPacked[nslots] (int2)
    const int histOfs = 0, cntOfs = 101;
    const int segOfs  = 204;                         // 16B-aligned
    int slotOfs = segOfs + B + 1;
    slotOfs = (slotOfs + 3) & ~3;                    // int2/16B alignment
    const size_t need = ((size_t)slotOfs + 2 * (size_t)nslots) * sizeof(int);
    const bool sortOK = (d_ws != nullptr) && (ws_size >= need) && (B <= 16384);

    if (sortOK) {
        int* wsi        = (int*)d_ws;
        int* hist       = wsi + histOfs;
        int* cnt        = wsi + cntOfs;
        int* segStart   = wsi + segOfs;
        int2* slotPacked = (int2*)(wsi + slotOfs);
        hipMemsetAsync(wsi, 0, 202 * sizeof(int), stream);
        const int p1blocks = (B + 1 + 255) / 256;    // 33
        seg_hist_kernel<<<p1blocks, 256, 0, stream>>>(index, segStart, hist, N, B);
        seg_scatter_kernel<<<16, 256, 0, stream>>>(segStart, hist, cnt, slotPacked, B, nslots);
        lstm12_kernel<<<nblocks, 256, 0, stream>>>(x, Wih, Whh, bih, bhh, index,
                                                   slotPacked, (float*)d_out, N, B);
    } else {
        lstm12_kernel<<<nblocks, 256, 0, stream>>>(x, Wih, Whh, bih, bhh, index,
                                                   nullptr, (float*)d_out, N, B);
    }
}